// Round 2
// baseline (1874.418 us; speedup 1.0000x reference)
//
#include <hip/hip_runtime.h>

#define NN 100000
#define NE 600000
#define DD 128
#define HID 512
#define NT 32
#define HPAD 516

// order-preserving float<->uint for atomic max
__device__ __forceinline__ unsigned f2ord(float f) {
  unsigned u = __float_as_uint(f);
  return (u & 0x80000000u) ? ~u : (u | 0x80000000u);
}
__device__ __forceinline__ float ord2f(unsigned e) {
  unsigned u = (e & 0x80000000u) ? (e ^ 0x80000000u) : ~e;
  return __uint_as_float(u);
}

__global__ __launch_bounds__(256) void scatter_k(
    const float* __restrict__ ea, const int* __restrict__ row,
    float* __restrict__ sum, unsigned* __restrict__ mx, int* __restrict__ cnt) {
  int gid = blockIdx.x * 256 + threadIdx.x;  // < 76.8M, fits int
  int e = gid >> 7;
  int d = gid & 127;
  int r = row[e];
  float v = ea[(size_t)e * DD + d];
  atomicAdd(sum + (size_t)r * DD + d, v);
  atomicMax(mx + (size_t)r * DD + d, f2ord(v));
  if (d == 0) atomicAdd(cnt + r, 1);
}

__global__ __launch_bounds__(256, 2) void mlp_k(
    const float* __restrict__ x, const float* __restrict__ sum,
    const unsigned* __restrict__ mx, const int* __restrict__ cnt,
    const int* __restrict__ batch, const float* __restrict__ u,
    const float* __restrict__ W1, const float* __restrict__ b1,
    const float* __restrict__ W2, const float* __restrict__ b2,
    float* __restrict__ out) {
  __shared__ __align__(16) float hT[NT][HPAD];   // concat-h, later reused as h1
  __shared__ __align__(16) float wbuf[2048];     // W1 4x512 panel / W2 16x128 panel

  const int tid = threadIdx.x;
  const int node0 = blockIdx.x * NT;

  // ---- gather: build concat([x, sum, max, mean]) tile + u scalar ----
  for (int idx = tid; idx < NT * DD; idx += 256) {
    const int i = idx >> 7, d = idx & 127;
    const int n = node0 + i;
    const int c = cnt[n];
    const float sv = sum[(size_t)n * DD + d];
    hT[i][d]       = x[(size_t)n * DD + d];
    hT[i][128 + d] = sv;
    hT[i][256 + d] = (c > 0) ? ord2f(mx[(size_t)n * DD + d]) : 0.f;
    hT[i][384 + d] = sv / fmaxf((float)c, 1.f);
  }
  if (tid < NT) {
    hT[tid][512] = u[batch[node0 + tid]];
  }

  const int ng = tid >> 5;   // 0..7  (node group)
  const int jg = tid & 31;   // 0..31 (col group)

  // ---- GEMM1: h1[32][512] = relu(h @ W1[0:512] + u*W1[512] + b1) ----
  float acc[4][4][4];
#pragma unroll
  for (int a = 0; a < 4; ++a)
#pragma unroll
    for (int b = 0; b < 4; ++b)
#pragma unroll
      for (int c = 0; c < 4; ++c) acc[a][b][c] = 0.f;

  for (int k0 = 0; k0 < HID; k0 += 4) {
    __syncthreads();
    {  // stage W1 rows k0..k0+3 (2048 floats)
      const float4* src = (const float4*)(W1 + (size_t)k0 * HID);
      float4* dst = (float4*)wbuf;
      dst[tid] = src[tid];
      dst[tid + 256] = src[tid + 256];
    }
    __syncthreads();

    float hv[4][4];
#pragma unroll
    for (int nn = 0; nn < 4; ++nn) {
      float4 h4 = *(const float4*)&hT[ng + 8 * nn][k0];
      hv[nn][0] = h4.x; hv[nn][1] = h4.y; hv[nn][2] = h4.z; hv[nn][3] = h4.w;
    }
#pragma unroll
    for (int kk = 0; kk < 4; ++kk) {
#pragma unroll
      for (int t = 0; t < 4; ++t) {
        float4 w4 = *(const float4*)&wbuf[kk * HID + jg * 4 + 128 * t];
#pragma unroll
        for (int nn = 0; nn < 4; ++nn) {
          acc[nn][t][0] += hv[nn][kk] * w4.x;
          acc[nn][t][1] += hv[nn][kk] * w4.y;
          acc[nn][t][2] += hv[nn][kk] * w4.z;
          acc[nn][t][3] += hv[nn][kk] * w4.w;
        }
      }
    }
  }

  __syncthreads();  // all hT reads done before overwrite

  // epilogue 1: + b1 + u*W1[512,:], relu, write h1 into hT[i][0:512]
#pragma unroll
  for (int nn = 0; nn < 4; ++nn) {
    const int i = ng + 8 * nn;
    const float un = hT[i][512];   // disjoint from h1 writes (j<512)
#pragma unroll
    for (int t = 0; t < 4; ++t) {
      const int j = jg * 4 + 128 * t;
      float4 b4 = *(const float4*)&b1[j];
      float4 w5 = *(const float4*)&W1[(size_t)512 * HID + j];
      float4 r;
      r.x = fmaxf(acc[nn][t][0] + b4.x + un * w5.x, 0.f);
      r.y = fmaxf(acc[nn][t][1] + b4.y + un * w5.y, 0.f);
      r.z = fmaxf(acc[nn][t][2] + b4.z + un * w5.z, 0.f);
      r.w = fmaxf(acc[nn][t][3] + b4.w + un * w5.w, 0.f);
      *(float4*)&hT[i][j] = r;
    }
  }

  // ---- GEMM2: out = h1 @ W2 + b2 + x ----
  float a2[4][4];
#pragma unroll
  for (int a = 0; a < 4; ++a)
#pragma unroll
    for (int b = 0; b < 4; ++b) a2[a][b] = 0.f;

  for (int k0 = 0; k0 < HID; k0 += 16) {
    __syncthreads();
    {  // stage W2 rows k0..k0+15 (2048 floats)
      const float4* src = (const float4*)(W2 + (size_t)k0 * DD);
      float4* dst = (float4*)wbuf;
      dst[tid] = src[tid];
      dst[tid + 256] = src[tid + 256];
    }
    __syncthreads();
#pragma unroll
    for (int kq = 0; kq < 4; ++kq) {
      float hv[4][4];
#pragma unroll
      for (int nn = 0; nn < 4; ++nn) {
        float4 h4 = *(const float4*)&hT[ng + 8 * nn][k0 + kq * 4];
        hv[nn][0] = h4.x; hv[nn][1] = h4.y; hv[nn][2] = h4.z; hv[nn][3] = h4.w;
      }
#pragma unroll
      for (int kk = 0; kk < 4; ++kk) {
        float4 w4 = *(const float4*)&wbuf[(kq * 4 + kk) * DD + jg * 4];
#pragma unroll
        for (int nn = 0; nn < 4; ++nn) {
          a2[nn][0] += hv[nn][kk] * w4.x;
          a2[nn][1] += hv[nn][kk] * w4.y;
          a2[nn][2] += hv[nn][kk] * w4.z;
          a2[nn][3] += hv[nn][kk] * w4.w;
        }
      }
    }
  }

  // epilogue 2: + b2 + residual x
#pragma unroll
  for (int nn = 0; nn < 4; ++nn) {
    const int n = node0 + ng + 8 * nn;
    const int j = jg * 4;
    float4 b4 = *(const float4*)&b2[j];
    float4 xv = *(const float4*)&x[(size_t)n * DD + j];
    float4 r;
    r.x = a2[nn][0] + b4.x + xv.x;
    r.y = a2[nn][1] + b4.y + xv.y;
    r.z = a2[nn][2] + b4.z + xv.z;
    r.w = a2[nn][3] + b4.w + xv.w;
    *(float4*)&out[(size_t)n * DD + j] = r;
  }
}

extern "C" void kernel_launch(void* const* d_in, const int* in_sizes, int n_in,
                              void* d_out, int out_size, void* d_ws, size_t ws_size,
                              hipStream_t stream) {
  const float* x        = (const float*)d_in[0];
  const int*   eidx     = (const int*)d_in[1];   // [2, NE], row = first NE
  const float* ea       = (const float*)d_in[2];
  const float* u        = (const float*)d_in[3];
  const int*   batch    = (const int*)d_in[4];
  const float* W1       = (const float*)d_in[5];
  const float* b1       = (const float*)d_in[6];
  const float* W2       = (const float*)d_in[7];
  const float* b2       = (const float*)d_in[8];
  float* out = (float*)d_out;

  float*    sum = (float*)d_ws;
  int*      cnt = (int*)((char*)d_ws + (size_t)NN * DD * 4);
  unsigned* mx  = (unsigned*)d_out;   // d_out doubles as max scratch

  hipMemsetAsync(d_ws, 0, (size_t)NN * DD * 4 + (size_t)NN * 4, stream);
  hipMemsetAsync(d_out, 0, (size_t)NN * DD * 4, stream);

  scatter_k<<<(NE * DD) / 256, 256, 0, stream>>>(ea, eidx, sum, mx, cnt);
  mlp_k<<<NN / NT, 256, 0, stream>>>(x, sum, mx, cnt, batch, u, W1, b1, W2, b2, out);
}

// Round 5
// 1228.919 us; speedup vs baseline: 1.5253x; 1.5253x over previous
//
#include <hip/hip_runtime.h>

#define NN 100000
#define NE 600000
#define DD 128
#define HID 512
#define BM 64        // nodes per block in MLP kernel

typedef short bf16x8 __attribute__((ext_vector_type(8)));
typedef float f32x4  __attribute__((ext_vector_type(4)));

__device__ __forceinline__ unsigned short f2bf(float f) {
  unsigned u = __float_as_uint(f);
  unsigned r = (u + 0x7fffu + ((u >> 16) & 1u)) >> 16;   // RN-even
  return (unsigned short)r;
}

// swizzled element index into a [64][512] bf16 LDS tile (XOR on k bits 3..5)
__device__ __forceinline__ int swz(int row, int k) {
  return row * HID + (k ^ ((row & 7) << 3));
}

// ---------------- CSR build ----------------
__global__ __launch_bounds__(256) void hist_k(const int* __restrict__ row, int* __restrict__ deg) {
  int e = blockIdx.x * 256 + threadIdx.x;
  if (e < NE) atomicAdd(&deg[row[e]], 1);
}

__global__ __launch_bounds__(512) void scan1_k(const int* __restrict__ deg,
                                               int* __restrict__ part, int* __restrict__ bsum) {
  __shared__ int s[512];
  const int t = threadIdx.x;
  const int g = blockIdx.x * 512 + t;
  int v = (g < NN) ? deg[g] : 0;
  s[t] = v; __syncthreads();
  for (int off = 1; off < 512; off <<= 1) {
    int a = (t >= off) ? s[t - off] : 0;
    __syncthreads();
    s[t] += a;
    __syncthreads();
  }
  if (g < NN) part[g] = s[t] - v;          // exclusive within block
  if (t == 511) bsum[blockIdx.x] = s[511];
}

__global__ __launch_bounds__(256) void scan2_k(const int* __restrict__ bsum, int* __restrict__ btop, int nblk) {
  __shared__ int s[256];
  const int t = threadIdx.x;
  int v = (t < nblk) ? bsum[t] : 0;
  s[t] = v; __syncthreads();
  for (int off = 1; off < 256; off <<= 1) {
    int a = (t >= off) ? s[t - off] : 0;
    __syncthreads();
    s[t] += a;
    __syncthreads();
  }
  btop[t] = s[t] - v;                      // exclusive
}

__global__ __launch_bounds__(512) void scan3_k(int* __restrict__ offs, const int* __restrict__ btop,
                                               int* __restrict__ cursor) {
  int g = blockIdx.x * 512 + threadIdx.x;
  if (g < NN) {
    int o = offs[g] + btop[blockIdx.x];
    offs[g] = o;
    cursor[g] = o;
  }
}

__global__ __launch_bounds__(256) void fill_k(const int* __restrict__ row,
                                              int* __restrict__ cursor, int* __restrict__ elist) {
  int e = blockIdx.x * 256 + threadIdx.x;
  if (e < NE) {
    int p = atomicAdd(&cursor[row[e]], 1);
    elist[p] = e;
  }
}

// ---------------- weight convert + fragment swizzle ----------------
// W1sw tiles: (kt,ntg) kt=0..15, ntg=0..31; elem ((kt*32+ntg)*64+l)*8+j = bf16(W1[(kt*32+(l>>4)*8+j)*512 + ntg*16+(l&15)])
// W2sw tiles: (kt,ntg) kt=0..15, ntg=0..7
__global__ __launch_bounds__(256) void wconv_k(const float* __restrict__ W1, const float* __restrict__ W2,
                                               unsigned short* __restrict__ W1sw, unsigned short* __restrict__ W2sw) {
  int idx = blockIdx.x * 256 + threadIdx.x;
  if (idx < 512 * 512) {
    int j = idx & 7, l = (idx >> 3) & 63, ntg = (idx >> 9) & 31, kt = idx >> 14;
    int k = kt * 32 + (l >> 4) * 8 + j;
    int c = ntg * 16 + (l & 15);
    W1sw[idx] = f2bf(W1[k * HID + c]);
  } else {
    int i2 = idx - 512 * 512;
    if (i2 < 512 * 128) {
      int j = i2 & 7, l = (i2 >> 3) & 63, ntg = (i2 >> 9) & 7, kt = i2 >> 12;
      int k = kt * 32 + (l >> 4) * 8 + j;
      int c = ntg * 16 + (l & 15);
      W2sw[i2] = f2bf(W2[k * DD + c]);
    }
  }
}

// ---------------- fused gather + MLP (bf16 MFMA) ----------------
__global__ __launch_bounds__(256, 2) void mlp_k(
    const float* __restrict__ x, const float* __restrict__ ea,
    const int* __restrict__ deg, const int* __restrict__ offs, const int* __restrict__ elist,
    const int* __restrict__ batch, const float* __restrict__ u,
    const unsigned short* __restrict__ W1sw, const unsigned short* __restrict__ W2sw,
    const float* __restrict__ W1, const float* __restrict__ b1,
    const float* __restrict__ b2, float* __restrict__ out) {
  __shared__ unsigned short hS[BM * HID];   // swizzled bf16 tile: h, then h1 in place
  __shared__ float u_s[BM];

  const int tid = threadIdx.x;
  const int node0 = blockIdx.x * BM;
  const int nv = min(BM, NN - node0);

  if (tid < BM) {
    int n = node0 + tid;
    u_s[tid] = (tid < nv) ? u[batch[n]] : 0.f;
  }

  // ---- gather: 2 groups of 128 threads; group owns one node at a time, lane owns channel d ----
  {
    const int grp = tid >> 7;          // 0,1
    const int d   = tid & 127;
    for (int q = 0; q < BM / 2; ++q) {
      const int i = grp * (BM / 2) + q;
      if (i < nv) {
        const int n   = node0 + i;
        const int beg = offs[n];
        const int dg  = deg[n];
        float s = 0.f, mxv = -3.0e38f;
        int e = dg ? elist[beg] : 0;
        for (int t = 0; t < dg; ++t) {
          int en = (t + 1 < dg) ? elist[beg + t + 1] : 0;
          float v = ea[(size_t)e * DD + d];
          s += v;
          mxv = fmaxf(mxv, v);
          e = en;
        }
        if (!dg) mxv = 0.f;
        float mean = s / fmaxf((float)dg, 1.f);
        float xv = x[(size_t)n * DD + d];
        hS[swz(i, d)]            = f2bf(xv);
        hS[swz(i, DD + d)]       = f2bf(s);
        hS[swz(i, 2 * DD + d)]   = f2bf(mxv);
        hS[swz(i, 3 * DD + d)]   = f2bf(mean);
      } else {
        hS[swz(i, d)] = 0; hS[swz(i, DD + d)] = 0;
        hS[swz(i, 2 * DD + d)] = 0; hS[swz(i, 3 * DD + d)] = 0;
      }
    }
  }
  __syncthreads();

  const int w = tid >> 6;    // wave 0..3
  const int l = tid & 63;
  const int lr = l & 15;     // row/col-in-tile index
  const int lk = l >> 4;     // k-chunk

  // ---- GEMM1: h1[64][512] = relu(h @ W1 + b1 + u*W1[512,:]) ----
  f32x4 acc[4][8];
#pragma unroll
  for (int m = 0; m < 4; ++m)
#pragma unroll
    for (int nt = 0; nt < 8; ++nt) acc[m][nt] = (f32x4)0.f;

  const bf16x8* w1p = (const bf16x8*)W1sw;
  for (int kt = 0; kt < 16; ++kt) {
    bf16x8 a[4];
#pragma unroll
    for (int m = 0; m < 4; ++m)
      a[m] = *(const bf16x8*)&hS[swz(m * 16 + lr, kt * 32 + lk * 8)];
    bf16x8 b[8];
#pragma unroll
    for (int nt = 0; nt < 8; ++nt)
      b[nt] = w1p[(kt * 32 + w * 8 + nt) * 64 + l];
#pragma unroll
    for (int m = 0; m < 4; ++m)
#pragma unroll
      for (int nt = 0; nt < 8; ++nt)
        acc[m][nt] = __builtin_amdgcn_mfma_f32_16x16x32_bf16(a[m], b[nt], acc[m][nt], 0, 0, 0);
  }

  __syncthreads();   // everyone done reading h

  // epilogue 1: bias + u-column + relu -> bf16 back into hS
#pragma unroll
  for (int m = 0; m < 4; ++m) {
#pragma unroll
    for (int nt = 0; nt < 8; ++nt) {
      const int col = w * 128 + nt * 16 + lr;
      const float bb = b1[col];
      const float wl = W1[(size_t)512 * HID + col];
#pragma unroll
      for (int r = 0; r < 4; ++r) {
        const int rw = m * 16 + lk * 4 + r;
        float val = acc[m][nt][r] + bb + u_s[rw] * wl;
        val = fmaxf(val, 0.f);
        hS[swz(rw, col)] = f2bf(val);
      }
    }
  }
  __syncthreads();

  // ---- GEMM2: out = h1 @ W2 + b2 + x ----
  f32x4 acc2[4][2];
#pragma unroll
  for (int m = 0; m < 4; ++m)
#pragma unroll
    for (int nt = 0; nt < 2; ++nt) acc2[m][nt] = (f32x4)0.f;

  const bf16x8* w2p = (const bf16x8*)W2sw;
  for (int kt = 0; kt < 16; ++kt) {
    bf16x8 a[4];
#pragma unroll
    for (int m = 0; m < 4; ++m)
      a[m] = *(const bf16x8*)&hS[swz(m * 16 + lr, kt * 32 + lk * 8)];
    bf16x8 b[2];
#pragma unroll
    for (int nt = 0; nt < 2; ++nt)
      b[nt] = w2p[(kt * 8 + w * 2 + nt) * 64 + l];
#pragma unroll
    for (int m = 0; m < 4; ++m)
#pragma unroll
      for (int nt = 0; nt < 2; ++nt)
        acc2[m][nt] = __builtin_amdgcn_mfma_f32_16x16x32_bf16(a[m], b[nt], acc2[m][nt], 0, 0, 0);
  }

  // epilogue 2: + b2 + residual x, store f32
#pragma unroll
  for (int m = 0; m < 4; ++m) {
#pragma unroll
    for (int nt = 0; nt < 2; ++nt) {
      const int col = (w * 2 + nt) * 16 + lr;
      const float bb = b2[col];
#pragma unroll
      for (int r = 0; r < 4; ++r) {
        const int rw = m * 16 + lk * 4 + r;
        const int n = node0 + rw;
        if (n < NN) {
          const size_t o = (size_t)n * DD + col;
          out[o] = acc2[m][nt][r] + bb + x[o];
        }
      }
    }
  }
}

extern "C" void kernel_launch(void* const* d_in, const int* in_sizes, int n_in,
                              void* d_out, int out_size, void* d_ws, size_t ws_size,
                              hipStream_t stream) {
  const float* x     = (const float*)d_in[0];
  const int*   eidx  = (const int*)d_in[1];   // [2, NE]; first NE = row (source)
  const float* ea    = (const float*)d_in[2];
  const float* u     = (const float*)d_in[3];
  const int*   batch = (const int*)d_in[4];
  const float* W1    = (const float*)d_in[5];
  const float* b1    = (const float*)d_in[6];
  const float* W2    = (const float*)d_in[7];
  const float* b2    = (const float*)d_in[8];
  float* out = (float*)d_out;

  char* ws = (char*)d_ws;
  unsigned short* W1sw = (unsigned short*)(ws);                    // 512*512*2 = 524288
  unsigned short* W2sw = (unsigned short*)(ws + 524288);           // 512*128*2 = 131072
  int* deg    = (int*)(ws + 655360);                               // 400000
  int* offs   = (int*)(ws + 1055360);                              // 400000
  int* cursor = (int*)(ws + 1455360);                              // 400000
  int* elist  = (int*)(ws + 1855360);                              // 2400000
  int* bsum   = (int*)(ws + 4255360);                              // 1024
  int* btop   = (int*)(ws + 4256384);                              // 1024

  const int nblk = (NN + 511) / 512;   // 196

  hipMemsetAsync(deg, 0, (size_t)NN * 4, stream);
  hist_k<<<(NE + 255) / 256, 256, 0, stream>>>(eidx, deg);
  scan1_k<<<nblk, 512, 0, stream>>>(deg, offs, bsum);
  scan2_k<<<1, 256, 0, stream>>>(bsum, btop, nblk);
  scan3_k<<<nblk, 512, 0, stream>>>(offs, btop, cursor);
  fill_k<<<(NE + 255) / 256, 256, 0, stream>>>(eidx, cursor, elist);
  wconv_k<<<(512 * 512 + 512 * 128 + 255) / 256, 256, 0, stream>>>(W1, W2, W1sw, W2sw);
  mlp_k<<<(NN + BM - 1) / BM, 256, 0, stream>>>(x, ea, deg, offs, elist, batch, u,
                                                W1sw, W2sw, W1, b1, b2, out);
}